// Round 2
// baseline (560.736 us; speedup 1.0000x reference)
//
#include <hip/hip_runtime.h>

#define NN 512
#define MM 512
#define KD 64
#define BIGF 1e30f
#define LOG2E 1.4426950408889634f
#define LN2F 0.6931471805599453f

// ---------------------------------------------------------------------------
// Kernel A: D[b,i,j] = ||x_i||^2 + ||y_j||^2 - 2 x_i . y_j   (unchanged)
// ---------------------------------------------------------------------------
__global__ __launch_bounds__(256) void compute_D_kernel(
    const float* __restrict__ x, const float* __restrict__ y,
    float* __restrict__ D) {
  __shared__ float xs[64][65];
  __shared__ float ys[64][65];
  __shared__ float x2s[64];
  __shared__ float y2s[64];

  const int b   = blockIdx.z;
  const int i0  = blockIdx.y * 64;
  const int j0  = blockIdx.x * 64;
  const int tid = threadIdx.x;

  const float4* xg = (const float4*)(x + ((size_t)b * NN + i0) * KD);
  const float4* yg = (const float4*)(y + ((size_t)b * MM + j0) * KD);
#pragma unroll
  for (int u = 0; u < 4; ++u) {
    int idx = tid + u * 256;
    int row = idx >> 4;
    int c4  = idx & 15;
    float4 v = xg[row * 16 + c4];
    xs[row][c4 * 4 + 0] = v.x; xs[row][c4 * 4 + 1] = v.y;
    xs[row][c4 * 4 + 2] = v.z; xs[row][c4 * 4 + 3] = v.w;
    float4 w = yg[row * 16 + c4];
    ys[row][c4 * 4 + 0] = w.x; ys[row][c4 * 4 + 1] = w.y;
    ys[row][c4 * 4 + 2] = w.z; ys[row][c4 * 4 + 3] = w.w;
  }
  __syncthreads();

  if (tid < 64) {
    float s = 0.f;
#pragma unroll
    for (int k = 0; k < KD; ++k) { float a = xs[tid][k]; s = fmaf(a, a, s); }
    x2s[tid] = s;
  } else if (tid < 128) {
    int r = tid - 64;
    float s = 0.f;
#pragma unroll
    for (int k = 0; k < KD; ++k) { float a = ys[r][k]; s = fmaf(a, a, s); }
    y2s[r] = s;
  }

  const int tx = tid & 15;
  const int ty = tid >> 4;
  float acc[4][4];
#pragma unroll
  for (int r = 0; r < 4; ++r)
#pragma unroll
    for (int c = 0; c < 4; ++c) acc[r][c] = 0.f;

#pragma unroll 4
  for (int k = 0; k < KD; ++k) {
    float a0 = xs[ty * 4 + 0][k];
    float a1 = xs[ty * 4 + 1][k];
    float a2 = xs[ty * 4 + 2][k];
    float a3 = xs[ty * 4 + 3][k];
    float b0 = ys[tx * 4 + 0][k];
    float b1 = ys[tx * 4 + 1][k];
    float b2 = ys[tx * 4 + 2][k];
    float b3 = ys[tx * 4 + 3][k];
    acc[0][0] = fmaf(a0, b0, acc[0][0]); acc[0][1] = fmaf(a0, b1, acc[0][1]);
    acc[0][2] = fmaf(a0, b2, acc[0][2]); acc[0][3] = fmaf(a0, b3, acc[0][3]);
    acc[1][0] = fmaf(a1, b0, acc[1][0]); acc[1][1] = fmaf(a1, b1, acc[1][1]);
    acc[1][2] = fmaf(a1, b2, acc[1][2]); acc[1][3] = fmaf(a1, b3, acc[1][3]);
    acc[2][0] = fmaf(a2, b0, acc[2][0]); acc[2][1] = fmaf(a2, b1, acc[2][1]);
    acc[2][2] = fmaf(a2, b2, acc[2][2]); acc[2][3] = fmaf(a2, b3, acc[2][3]);
    acc[3][0] = fmaf(a3, b0, acc[3][0]); acc[3][1] = fmaf(a3, b1, acc[3][1]);
    acc[3][2] = fmaf(a3, b2, acc[3][2]); acc[3][3] = fmaf(a3, b3, acc[3][3]);
  }
  __syncthreads();

  float yq[4];
#pragma unroll
  for (int c = 0; c < 4; ++c) yq[c] = y2s[tx * 4 + c];
#pragma unroll
  for (int r = 0; r < 4; ++r) {
    float xq = x2s[ty * 4 + r];
    float4 o;
    o.x = xq + yq[0] - 2.f * acc[r][0];
    o.y = xq + yq[1] - 2.f * acc[r][1];
    o.z = xq + yq[2] - 2.f * acc[r][2];
    o.w = xq + yq[3] - 2.f * acc[r][3];
    float4* dst =
        (float4*)(D + ((size_t)b * NN + i0 + ty * 4 + r) * MM + j0 + tx * 4);
    *dst = o;
  }
}

// ---------------------------------------------------------------------------
// Kernel B: anti-diagonal DP, 256 threads, 2 rows/thread (rows 2t, 2t+1).
//  - row 2t+1's up-neighbor (row 2t) is thread-local -> registers a1/a2
//  - only row 2t+1 is published to LDS; row 2t-1 read from thread t-1
//  - p-2 neighbor value register-carried (vprev) -> 1 LDS read + 1 write/iter
//  - D row consumed sequentially -> 3-deep float4 register prefetch queue
//    (chunk +2 ahead = ~8 iterations of load lookahead)
// log2-domain softmin: softmin' = mn - log2(sum 2^(mn-rk)), R' = R*log2e
// ---------------------------------------------------------------------------
__device__ __forceinline__ float extract4(float4 q, int e) {
  float lo = (e & 1) ? q.y : q.x;
  float hi = (e & 1) ? q.w : q.z;
  return (e & 2) ? hi : lo;
}

__global__ __launch_bounds__(256) void softdtw_dp_kernel(
    const float* __restrict__ D, float* __restrict__ out) {
  __shared__ float buf[2][256];
  const int b = blockIdx.x;
  const int t = threadIdx.x;
  const int rowA = 2 * t;
  const float* __restrict__ DA = D + ((size_t)b * NN + rowA) * MM;
  const float* __restrict__ DB = DA + MM;  // row 2t+1

  // register prefetch queues (aligned float4 chunks of each D row)
  float4 qa0 = ((const float4*)DA)[0];
  float4 qa1 = ((const float4*)DA)[1];
  float4 qa2 = ((const float4*)DA)[2];
  float4 qb0 = ((const float4*)DB)[0];
  float4 qb1 = ((const float4*)DB)[1];
  float4 qb2 = ((const float4*)DB)[2];

  float a1 = BIGF, a2 = BIGF;  // row 2t values at diag p-1, p-2
  float bl = BIGF;             // row 2t+1 value at diag p-1 (left dep)
  float vprev = BIGF;          // row 2t-1 value at diag p-2 (register-carried)
  const int tm = (t == 0) ? 0 : t - 1;
  const bool t0 = (t == 0);

#pragma unroll 2
  for (int p = 0; p < NN + MM - 1; ++p) {
    const int ja = p - rowA;   // column of row 2t on this diagonal
    const int jb = ja - 1;     // column of row 2t+1

    // LDS read first: row 2t-1 at diag p-1 (written by thread t-1 last iter)
    float v = buf[(p + 1) & 1][tm];

    // queue rotation BEFORE extraction (entering a new chunk this iter)
    if (ja > 0 && ja < MM && (ja & 3) == 0) {
      qa0 = qa1; qa1 = qa2;
      int c = (ja >> 2) + 2; c = c > 127 ? 127 : c;
      qa2 = ((const float4*)DA)[c];
    }
    if (jb > 0 && jb < MM && (jb & 3) == 0) {
      qb0 = qb1; qb1 = qb2;
      int c = (jb >> 2) + 2; c = c > 127 ? 127 : c;
      qb2 = ((const float4*)DB)[c];
    }
    float da = extract4(qa0, ja & 3);
    float db = extract4(qb0, jb & 3);

    // ---- cell B first: independent of the LDS read (hides its latency) ----
    // (rowB=2t+1, jb): up = row 2t @ p-1 (a1), diag = row 2t @ p-2 (a2),
    //                  left = row 2t+1 @ p-1 (bl)
    float mnB = fminf(a2, fminf(a1, bl));
    float sB = __builtin_amdgcn_exp2f(mnB - a2) +
               __builtin_amdgcn_exp2f(mnB - a1) +
               __builtin_amdgcn_exp2f(mnB - bl);
    float smB = mnB - __builtin_amdgcn_logf(sB);  // v_log_f32 is log2
    float newB = ((unsigned)jb < MM) ? fmaf(db, LOG2E, smB) : BIGF;

    // ---- cell A: (rowA=2t, ja): up = v, diag = vprev, left = a1 ----
    float r0A = t0 ? ((p == 0) ? 0.f : BIGF) : vprev;
    float r1A = t0 ? BIGF : v;
    float mnA = fminf(r0A, fminf(r1A, a1));
    float sA = __builtin_amdgcn_exp2f(mnA - r0A) +
               __builtin_amdgcn_exp2f(mnA - r1A) +
               __builtin_amdgcn_exp2f(mnA - a1);
    float smA = mnA - __builtin_amdgcn_logf(sA);
    float newA = ((unsigned)ja < MM) ? fmaf(da, LOG2E, smA) : BIGF;

    // publish row 2t+1 for thread t+1
    buf[p & 1][t] = newB;

    // rotate state
    vprev = v;
    a2 = a1; a1 = newA;
    bl = newB;

    __syncthreads();
  }

  if (t == 255) out[b] = bl * LN2F;  // cell (511,511) at p=1022
}

// ---------------------------------------------------------------------------
extern "C" void kernel_launch(void* const* d_in, const int* in_sizes, int n_in,
                              void* d_out, int out_size, void* d_ws,
                              size_t ws_size, hipStream_t stream) {
  const float* x = (const float*)d_in[0];
  const float* y = (const float*)d_in[1];
  float* out = (float*)d_out;
  float* D = (float*)d_ws;  // B*512*512*4 = 64 MB

  const int B = in_sizes[0] / (NN * KD);

  dim3 gA(MM / 64, NN / 64, B);
  compute_D_kernel<<<gA, 256, 0, stream>>>(x, y, D);
  softdtw_dp_kernel<<<B, 256, 0, stream>>>(D, out);
}

// Round 3
// 453.872 us; speedup vs baseline: 1.2354x; 1.2354x over previous
//
#include <hip/hip_runtime.h>

#define NN 512
#define MM 512
#define KD 64
#define BIGF 1e30f
#define LOG2E 1.4426950408889634f
#define LN2F 0.6931471805599453f

// ---------------------------------------------------------------------------
// Kernel A: D[b,i,j] = ||x_i||^2 + ||y_j||^2 - 2 x_i . y_j   (unchanged)
// ---------------------------------------------------------------------------
__global__ __launch_bounds__(256) void compute_D_kernel(
    const float* __restrict__ x, const float* __restrict__ y,
    float* __restrict__ D) {
  __shared__ float xs[64][65];
  __shared__ float ys[64][65];
  __shared__ float x2s[64];
  __shared__ float y2s[64];

  const int b   = blockIdx.z;
  const int i0  = blockIdx.y * 64;
  const int j0  = blockIdx.x * 64;
  const int tid = threadIdx.x;

  const float4* xg = (const float4*)(x + ((size_t)b * NN + i0) * KD);
  const float4* yg = (const float4*)(y + ((size_t)b * MM + j0) * KD);
#pragma unroll
  for (int u = 0; u < 4; ++u) {
    int idx = tid + u * 256;
    int row = idx >> 4;
    int c4  = idx & 15;
    float4 v = xg[row * 16 + c4];
    xs[row][c4 * 4 + 0] = v.x; xs[row][c4 * 4 + 1] = v.y;
    xs[row][c4 * 4 + 2] = v.z; xs[row][c4 * 4 + 3] = v.w;
    float4 w = yg[row * 16 + c4];
    ys[row][c4 * 4 + 0] = w.x; ys[row][c4 * 4 + 1] = w.y;
    ys[row][c4 * 4 + 2] = w.z; ys[row][c4 * 4 + 3] = w.w;
  }
  __syncthreads();

  if (tid < 64) {
    float s = 0.f;
#pragma unroll
    for (int k = 0; k < KD; ++k) { float a = xs[tid][k]; s = fmaf(a, a, s); }
    x2s[tid] = s;
  } else if (tid < 128) {
    int r = tid - 64;
    float s = 0.f;
#pragma unroll
    for (int k = 0; k < KD; ++k) { float a = ys[r][k]; s = fmaf(a, a, s); }
    y2s[r] = s;
  }

  const int tx = tid & 15;
  const int ty = tid >> 4;
  float acc[4][4];
#pragma unroll
  for (int r = 0; r < 4; ++r)
#pragma unroll
    for (int c = 0; c < 4; ++c) acc[r][c] = 0.f;

#pragma unroll 4
  for (int k = 0; k < KD; ++k) {
    float a0 = xs[ty * 4 + 0][k];
    float a1 = xs[ty * 4 + 1][k];
    float a2 = xs[ty * 4 + 2][k];
    float a3 = xs[ty * 4 + 3][k];
    float b0 = ys[tx * 4 + 0][k];
    float b1 = ys[tx * 4 + 1][k];
    float b2 = ys[tx * 4 + 2][k];
    float b3 = ys[tx * 4 + 3][k];
    acc[0][0] = fmaf(a0, b0, acc[0][0]); acc[0][1] = fmaf(a0, b1, acc[0][1]);
    acc[0][2] = fmaf(a0, b2, acc[0][2]); acc[0][3] = fmaf(a0, b3, acc[0][3]);
    acc[1][0] = fmaf(a1, b0, acc[1][0]); acc[1][1] = fmaf(a1, b1, acc[1][1]);
    acc[1][2] = fmaf(a1, b2, acc[1][2]); acc[1][3] = fmaf(a1, b3, acc[1][3]);
    acc[2][0] = fmaf(a2, b0, acc[2][0]); acc[2][1] = fmaf(a2, b1, acc[2][1]);
    acc[2][2] = fmaf(a2, b2, acc[2][2]); acc[2][3] = fmaf(a2, b3, acc[2][3]);
    acc[3][0] = fmaf(a3, b0, acc[3][0]); acc[3][1] = fmaf(a3, b1, acc[3][1]);
    acc[3][2] = fmaf(a3, b2, acc[3][2]); acc[3][3] = fmaf(a3, b3, acc[3][3]);
  }
  __syncthreads();

  float yq[4];
#pragma unroll
  for (int c = 0; c < 4; ++c) yq[c] = y2s[tx * 4 + c];
#pragma unroll
  for (int r = 0; r < 4; ++r) {
    float xq = x2s[ty * 4 + r];
    float4 o;
    o.x = xq + yq[0] - 2.f * acc[r][0];
    o.y = xq + yq[1] - 2.f * acc[r][1];
    o.z = xq + yq[2] - 2.f * acc[r][2];
    o.w = xq + yq[3] - 2.f * acc[r][3];
    float4* dst =
        (float4*)(D + ((size_t)b * NN + i0 + ty * 4 + r) * MM + j0 + tx * 4);
    *dst = o;
  }
}

// ---------------------------------------------------------------------------
// Kernel B: anti-diagonal DP, 256 threads, 2 rows/thread (rows 2t, 2t+1).
// KEY FIX vs round 2: __syncthreads drains vmcnt(0), so per-iteration global
// loads expose full memory latency every diagonal. D values are only ever
// consumed by the owning thread -> stage 32 diagonals' worth (32 floats per
// row, 64 scalar loads) into REGISTERS at block boundaries. Latency exposed
// once per 32 iterations instead of every iteration. Inner loop fully
// unrolled (static register indexing), zero global traffic inside.
// softmin via min3/med3/max3: exp2(mn-mn)==1 -> only 2 exp2 + 1 log per cell.
// log2-domain: softmin' = mn - log2(1 + 2^(mn-md) + 2^(mn-mx)), R' = R*log2e
// ---------------------------------------------------------------------------
__global__ __launch_bounds__(256) void softdtw_dp_kernel(
    const float* __restrict__ D, float* __restrict__ out) {
  __shared__ float buf[2][256];
  const int b = blockIdx.x;
  const int t = threadIdx.x;
  const int rowA = 2 * t;
  const float* __restrict__ DA = D + ((size_t)b * NN + rowA) * MM;
  const float* __restrict__ DB = DA + MM;  // row 2t+1

  float a1 = BIGF, a2 = BIGF;  // row 2t values at diag p-1, p-2
  float bl = BIGF;             // row 2t+1 value at diag p-1
  float vprev = BIGF;          // row 2t-1 value at diag p-2 (register-carried)
  const int tm = (t == 0) ? 0 : t - 1;
  const bool t0 = (t == 0);

  buf[0][t] = BIGF;
  buf[1][t] = BIGF;
  __syncthreads();

  for (int p0 = 0; p0 < 1023; p0 += 32) {
    // ---- stage this block's D values into registers (issued back-to-back;
    //      drained once at the first end-of-iteration barrier) ----
    float ra[32], rb[32];
#pragma unroll
    for (int q = 0; q < 32; ++q) {
      int ca = p0 + q - rowA;           // column of row 2t at diag p0+q
      ca = ca < 0 ? 0 : (ca > MM - 1 ? MM - 1 : ca);
      ra[q] = DA[ca];
    }
#pragma unroll
    for (int q = 0; q < 32; ++q) {
      int cb = p0 + q - rowA - 1;       // column of row 2t+1 at diag p0+q
      cb = cb < 0 ? 0 : (cb > MM - 1 ? MM - 1 : cb);
      rb[q] = DB[cb];
    }

#pragma unroll
    for (int q = 0; q < 32; ++q) {
      const int p = p0 + q;
      if (p < 1023) {  // uniform across block -> scalar branch, barrier safe
        const int ja = p - rowA;
        const int jb = ja - 1;

        // row 2t-1 at diag p-1 (written by thread t-1 last iteration)
        float v = buf[(p + 1) & 1][tm];

        // ---- cell B (row 2t+1, jb): deps all thread-local ----
        float mnB = fminf(a2, fminf(a1, bl));
        float mdB = __builtin_amdgcn_fmed3f(a2, a1, bl);
        float mxB = fmaxf(a2, fmaxf(a1, bl));
        float sB = 1.0f + __builtin_amdgcn_exp2f(mnB - mdB) +
                          __builtin_amdgcn_exp2f(mnB - mxB);
        float smB = mnB - __builtin_amdgcn_logf(sB);  // v_log_f32 is log2
        float newB = ((unsigned)jb < MM) ? fmaf(rb[q], LOG2E, smB) : BIGF;

        // ---- cell A (row 2t, ja): up = v, diag = vprev, left = a1 ----
        float r0A = t0 ? ((p == 0) ? 0.f : BIGF) : vprev;
        float r1A = t0 ? BIGF : v;
        float mnA = fminf(r0A, fminf(r1A, a1));
        float mdA = __builtin_amdgcn_fmed3f(r0A, r1A, a1);
        float mxA = fmaxf(r0A, fmaxf(r1A, a1));
        float sA = 1.0f + __builtin_amdgcn_exp2f(mnA - mdA) +
                          __builtin_amdgcn_exp2f(mnA - mxA);
        float smA = mnA - __builtin_amdgcn_logf(sA);
        float newA = ((unsigned)ja < MM) ? fmaf(ra[q], LOG2E, smA) : BIGF;

        // publish row 2t+1 for thread t+1
        buf[p & 1][t] = newB;

        vprev = v;
        a2 = a1; a1 = newA;
        bl = newB;

        __syncthreads();
      }
    }
  }

  if (t == 255) out[b] = bl * LN2F;  // cell (511,511) computed at p=1022
}

// ---------------------------------------------------------------------------
extern "C" void kernel_launch(void* const* d_in, const int* in_sizes, int n_in,
                              void* d_out, int out_size, void* d_ws,
                              size_t ws_size, hipStream_t stream) {
  const float* x = (const float*)d_in[0];
  const float* y = (const float*)d_in[1];
  float* out = (float*)d_out;
  float* D = (float*)d_ws;  // B*512*512*4 = 64 MB

  const int B = in_sizes[0] / (NN * KD);

  dim3 gA(MM / 64, NN / 64, B);
  compute_D_kernel<<<gA, 256, 0, stream>>>(x, y, D);
  softdtw_dp_kernel<<<B, 256, 0, stream>>>(D, out);
}

// Round 4
// 413.659 us; speedup vs baseline: 1.3555x; 1.0972x over previous
//
#include <hip/hip_runtime.h>

#define NN 512
#define MM 512
#define KD 64
#define BIGF 1e30f
#define LOG2E 1.4426950408889634f
#define LN2F 0.6931471805599453f
#define BATCH_STRIDE (NN * MM)  // packed diagonal-major floats per batch

// Packed diagonal layout, per batch: diagonal p (= i+j, 0..1022) occupies
// slots [start(p), start(p)+len(p)) where len(p) = min(p+1, 1023-p, 512),
// cell (i, p-i) at slot start(p) + i - lo(p), lo(p) = max(0, p-511).
//   p <= 511:  start(p) = p(p+1)/2,                      lo = 0
//   p >= 512:  start(p) = 131328 + (p-512)(1535-p)/2,    lo = p-511
// Total = 512*512 exactly -> same 64 MB workspace.

typedef float f32x4 __attribute__((ext_vector_type(4), aligned(4)));

// ---------------------------------------------------------------------------
// Kernel A: D = ||x_i||^2 + ||y_j||^2 - 2 x.y, written in PACKED DIAGONAL
// layout. Compute identical to round 3 (verified); only the stores changed
// to scatter via a per-block start-offset table (127 entries in LDS).
// ---------------------------------------------------------------------------
__global__ __launch_bounds__(256) void compute_D_kernel(
    const float* __restrict__ x, const float* __restrict__ y,
    float* __restrict__ Dp) {
  __shared__ float xs[64][65];
  __shared__ float ys[64][65];
  __shared__ float x2s[64];
  __shared__ float y2s[64];
  __shared__ int off_tab[127];  // start(p) - lo(p) for p = pb..pb+126

  const int b   = blockIdx.z;
  const int i0  = blockIdx.y * 64;
  const int j0  = blockIdx.x * 64;
  const int pb  = i0 + j0;
  const int tid = threadIdx.x;

  const float4* xg = (const float4*)(x + ((size_t)b * NN + i0) * KD);
  const float4* yg = (const float4*)(y + ((size_t)b * MM + j0) * KD);
#pragma unroll
  for (int u = 0; u < 4; ++u) {
    int idx = tid + u * 256;
    int row = idx >> 4;
    int c4  = idx & 15;
    float4 v = xg[row * 16 + c4];
    xs[row][c4 * 4 + 0] = v.x; xs[row][c4 * 4 + 1] = v.y;
    xs[row][c4 * 4 + 2] = v.z; xs[row][c4 * 4 + 3] = v.w;
    float4 w = yg[row * 16 + c4];
    ys[row][c4 * 4 + 0] = w.x; ys[row][c4 * 4 + 1] = w.y;
    ys[row][c4 * 4 + 2] = w.z; ys[row][c4 * 4 + 3] = w.w;
  }
  __syncthreads();

  if (tid < 64) {
    float s = 0.f;
#pragma unroll
    for (int k = 0; k < KD; ++k) { float a = xs[tid][k]; s = fmaf(a, a, s); }
    x2s[tid] = s;
  } else if (tid < 128) {
    int r = tid - 64;
    float s = 0.f;
#pragma unroll
    for (int k = 0; k < KD; ++k) { float a = ys[r][k]; s = fmaf(a, a, s); }
    y2s[r] = s;
  } else if (tid < 255) {
    int q = tid - 128;  // 0..126
    int p = pb + q;
    int st, lo;
    if (p < 512) { st = p * (p + 1) / 2;                       lo = 0; }
    else         { st = 131328 + (p - 512) * (1535 - p) / 2;   lo = p - 511; }
    off_tab[q] = st - lo;
  }

  const int tx = tid & 15;
  const int ty = tid >> 4;
  float acc[4][4];
#pragma unroll
  for (int r = 0; r < 4; ++r)
#pragma unroll
    for (int c = 0; c < 4; ++c) acc[r][c] = 0.f;

#pragma unroll 4
  for (int k = 0; k < KD; ++k) {
    float a0 = xs[ty * 4 + 0][k];
    float a1 = xs[ty * 4 + 1][k];
    float a2 = xs[ty * 4 + 2][k];
    float a3 = xs[ty * 4 + 3][k];
    float b0 = ys[tx * 4 + 0][k];
    float b1 = ys[tx * 4 + 1][k];
    float b2 = ys[tx * 4 + 2][k];
    float b3 = ys[tx * 4 + 3][k];
    acc[0][0] = fmaf(a0, b0, acc[0][0]); acc[0][1] = fmaf(a0, b1, acc[0][1]);
    acc[0][2] = fmaf(a0, b2, acc[0][2]); acc[0][3] = fmaf(a0, b3, acc[0][3]);
    acc[1][0] = fmaf(a1, b0, acc[1][0]); acc[1][1] = fmaf(a1, b1, acc[1][1]);
    acc[1][2] = fmaf(a1, b2, acc[1][2]); acc[1][3] = fmaf(a1, b3, acc[1][3]);
    acc[2][0] = fmaf(a2, b0, acc[2][0]); acc[2][1] = fmaf(a2, b1, acc[2][1]);
    acc[2][2] = fmaf(a2, b2, acc[2][2]); acc[2][3] = fmaf(a2, b3, acc[2][3]);
    acc[3][0] = fmaf(a3, b0, acc[3][0]); acc[3][1] = fmaf(a3, b1, acc[3][1]);
    acc[3][2] = fmaf(a3, b2, acc[3][2]); acc[3][3] = fmaf(a3, b3, acc[3][3]);
  }
  __syncthreads();  // x2s/y2s/off_tab ready

  float* Db = Dp + (size_t)b * BATCH_STRIDE;
  float yq[4];
#pragma unroll
  for (int c = 0; c < 4; ++c) yq[c] = y2s[tx * 4 + c];
#pragma unroll
  for (int r = 0; r < 4; ++r) {
    float xq = x2s[ty * 4 + r];
    int i = i0 + ty * 4 + r;
#pragma unroll
    for (int c = 0; c < 4; ++c) {
      float val = xq + yq[c] - 2.f * acc[r][c];
      int q = ty * 4 + r + tx * 4 + c;  // p - pb, 0..126
      Db[off_tab[q] + i] = val;
    }
  }
}

// ---------------------------------------------------------------------------
// Kernel B: softDTW DP, ONE WAVE per batch, 8 rows per lane, NO barriers.
//  - cross-lane dep (row 8L-1 -> row 8L) via __shfl_up, register-to-register
//  - packed diagonal layout -> each diagonal = 8 contiguous floats/lane,
//    2 unaligned-ok dwordx4 loads, coalesced across lanes
//  - double-buffered 2 diagonals ahead; no __syncthreads -> loads stay in
//    flight (the vmcnt(0) barrier-drain of rounds 1-3 is structurally gone)
//  - unroll-2 with C1/C2 role swap -> zero register rotation movs
// softmin (log2 domain): exp2(mn-mn)==1 -> 2 exp2 + 1 log per cell.
// ---------------------------------------------------------------------------
__global__ __launch_bounds__(64) void softdtw_dp_kernel(
    const float* __restrict__ Dp, float* __restrict__ out) {
  const int b = blockIdx.x;
  const int L = threadIdx.x;        // lane 0..63
  const int rbase = 8 * L;          // first row owned by this lane
  const float* __restrict__ base = Dp + (size_t)b * BATCH_STRIDE;

  float C1[8], C2[8];               // row values at diagonals p-1 / p-2
#pragma unroll
  for (int r = 0; r < 8; ++r) { C1[r] = BIGF; C2[r] = BIGF; }
  float up1 = BIGF;                     // row rbase-1 @ p-1 (from lane L-1)
  float up2 = (L == 0) ? 0.f : BIGF;    // row rbase-1 @ p-2; 0 seeds cell (0,0)

  // prefetch buffers: diag p -> B0, diag p+1 -> B1 (8 floats per lane each)
  f32x4 B0a, B0b, B1a, B1b;
  {
    const float* q0 = base + 0 + rbase;  // off(0) = 0
    B0a = *(const f32x4*)q0;  B0b = *(const f32x4*)(q0 + 4);
    const float* q1 = base + 1 + rbase;  // off(1) = 1
    B1a = *(const f32x4*)q1;  B1b = *(const f32x4*)(q1 + 4);
  }
  // scalar chain for the next diagonal to load (p_ld), off(2)=3, len(2)=3
  int off_ld = 3, p_ld = 2, len_ld = 3;

  int jL = -rbase;  // column of row rbase at current diagonal p

  // one DP step for diagonal at column-base jl: prev diag in cp[], diag p-2
  // in cd[] (overwritten in place with the new values)
  auto STEP = [&](float (&cp)[8], float (&cd)[8], f32x4 da, f32x4 db, int jl) {
    float carry = up2;  // row-1 value @ p-2 for r=0
#pragma unroll
    for (int r = 0; r < 8; ++r) {
      float dg = carry;                       // R(row-1, j-1)
      carry = cd[r];                          // save old p-2 value for r+1
      float up = (r == 0) ? up1 : cp[r - 1];  // R(row-1, j)
      float lf = cp[r];                       // R(row,   j-1)
      float mn = fminf(dg, fminf(up, lf));
      float md = __builtin_amdgcn_fmed3f(dg, up, lf);
      float mx = fmaxf(dg, fmaxf(up, lf));
      float s  = 1.0f + __builtin_amdgcn_exp2f(mn - md) +
                        __builtin_amdgcn_exp2f(mn - mx);
      float sm = mn - __builtin_amdgcn_logf(s);  // v_log_f32 is log2
      float dv = (r == 0) ? da.x : (r == 1) ? da.y : (r == 2) ? da.z :
                 (r == 3) ? da.w : (r == 4) ? db.x : (r == 5) ? db.y :
                 (r == 6) ? db.z : db.w;
      cd[r] = ((unsigned)(jl - r) < (unsigned)MM) ? fmaf(dv, LOG2E, sm) : BIGF;
    }
    float t = __shfl_up(cd[7], 1, 64);
    up2 = up1;
    up1 = (L == 0) ? BIGF : t;
  };

  for (int p = 0; p < 1022; p += 2) {
    // diag p: uses B0, writes C2
    STEP(C1, C2, B0a, B0b, jL);
    {  // reload B0 <- diag p+2
      const float* q = base + off_ld + rbase;
      B0a = *(const f32x4*)q;  B0b = *(const f32x4*)(q + 4);
      off_ld += len_ld - (p_ld >= 511 ? 1 : 0);
      ++p_ld;
      len_ld = (p_ld < 512) ? p_ld + 1 : 1023 - p_ld;
    }
    ++jL;
    // diag p+1: uses B1, writes C1
    STEP(C2, C1, B1a, B1b, jL);
    {  // reload B1 <- diag p+3 (last one reads in-bounds garbage, unused)
      const float* q = base + off_ld + rbase;
      B1a = *(const f32x4*)q;  B1b = *(const f32x4*)(q + 4);
      off_ld += len_ld - (p_ld >= 511 ? 1 : 0);
      ++p_ld;
      len_ld = (p_ld < 512) ? p_ld + 1 : 1023 - p_ld;
    }
    ++jL;
  }
  // tail diagonal p = 1022 (roles back to start: C1 = p-1, C2 = p-2)
  STEP(C1, C2, B0a, B0b, jL);

  if (L == 63) out[b] = C2[7] * LN2F;  // cell (511, 511)
}

// ---------------------------------------------------------------------------
extern "C" void kernel_launch(void* const* d_in, const int* in_sizes, int n_in,
                              void* d_out, int out_size, void* d_ws,
                              size_t ws_size, hipStream_t stream) {
  const float* x = (const float*)d_in[0];
  const float* y = (const float*)d_in[1];
  float* out = (float*)d_out;
  float* Dp = (float*)d_ws;  // 64 MB packed diagonal-major

  const int B = in_sizes[0] / (NN * KD);

  dim3 gA(MM / 64, NN / 64, B);
  compute_D_kernel<<<gA, 256, 0, stream>>>(x, y, Dp);
  softdtw_dp_kernel<<<B, 64, 0, stream>>>(Dp, out);
}